// Round 7
// baseline (424.381 us; speedup 1.0000x reference)
//
#include <hip/hip_runtime.h>
#include <hip/hip_bf16.h>
#include <math.h>

#define NE    8
#define KTOP  2
#define CDIM  1024
#define HDIM  4096
#define NTOK  8192
#define CAPE  1280
#define NSLOT (NTOK * KTOP)

typedef __bf16 bf16x8 __attribute__((ext_vector_type(8)));
typedef __bf16 bf16x4 __attribute__((ext_vector_type(4)));
typedef __bf16 bf16x2 __attribute__((ext_vector_type(2)));
typedef float  f32x4  __attribute__((ext_vector_type(4)));

#define GAS __attribute__((address_space(1)))
#define LAS __attribute__((address_space(3)))

// ---------------------------------------------------------------------------
// Transposing fp32 -> bf16 weight conversion: src [E][R][Cc] -> dst [E][Cc][R]
// ---------------------------------------------------------------------------
__global__ __launch_bounds__(256) void k_transpose_bf16(
    const float* __restrict__ src, __bf16* __restrict__ dst, int R, int Cc)
{
    __shared__ float tile[32][33];
    const int e  = blockIdx.z;
    const int cb = blockIdx.x * 32;
    const int rb = blockIdx.y * 32;
    const int t  = threadIdx.x;
    const int tx = t & 31, ty = t >> 5;
    const float* s = src + (size_t)e * R * Cc;
    __bf16*      d = dst + (size_t)e * R * Cc;
#pragma unroll
    for (int i = 0; i < 32; i += 8)
        tile[ty + i][tx] = s[(size_t)(rb + ty + i) * Cc + cb + tx];
    __syncthreads();
    const int op  = t & 15;      // src-row pair
    const int oc0 = t >> 4;      // out-row base (0..15)
#pragma unroll
    for (int j = 0; j < 2; ++j) {
        const int oc = oc0 + j * 16;
        bf16x2 v;
        v[0] = (__bf16)tile[op * 2][oc];
        v[1] = (__bf16)tile[op * 2 + 1][oc];
        *(bf16x2*)(d + (size_t)(cb + oc) * R + rb + op * 2) = v;
    }
}

// ---------------------------------------------------------------------------
// Router: fp32 logits -> softmax -> top2 -> normalized gates. 1 wave = 1 token.
// ---------------------------------------------------------------------------
__global__ __launch_bounds__(256) void k_router(
    const float* __restrict__ x, const float* __restrict__ rw,
    const float* __restrict__ rb, float* __restrict__ probs,
    float* __restrict__ gates, int* __restrict__ tidx)
{
    __shared__ float rws[NE * CDIM];
    const int tid = threadIdx.x;
    for (int i = tid; i < NE * CDIM / 4; i += 256)
        ((float4*)rws)[i] = ((const float4*)rw)[i];
    __syncthreads();

    const int wave = tid >> 6, lane = tid & 63;
    const int n = blockIdx.x * 4 + wave;
    const float* xr = x + (size_t)n * CDIM;

    float acc[NE];
#pragma unroll
    for (int e = 0; e < NE; ++e) acc[e] = 0.f;
    for (int j = 0; j < CDIM / 64; ++j) {
        const float xv = xr[j * 64 + lane];
#pragma unroll
        for (int e = 0; e < NE; ++e) acc[e] += xv * rws[e * CDIM + j * 64 + lane];
    }
#pragma unroll
    for (int off = 32; off > 0; off >>= 1) {
#pragma unroll
        for (int e = 0; e < NE; ++e) acc[e] += __shfl_down(acc[e], off);
    }
    if (lane == 0) {
        float mx = -1e30f;
#pragma unroll
        for (int e = 0; e < NE; ++e) { acc[e] += rb[e]; mx = fmaxf(mx, acc[e]); }
        float p[NE], s = 0.f;
#pragma unroll
        for (int e = 0; e < NE; ++e) { p[e] = expf(acc[e] - mx); s += p[e]; }
        const float inv = 1.f / s;
#pragma unroll
        for (int e = 0; e < NE; ++e) { p[e] *= inv; probs[(size_t)n * NE + e] = p[e]; }
        int   i1 = 0;  float v1 = p[0];
        int   i2 = -1; float v2 = -1.f;
#pragma unroll
        for (int e = 1; e < NE; ++e) {
            if (p[e] > v1)      { v2 = v1; i2 = i1; v1 = p[e]; i1 = e; }
            else if (p[e] > v2) { v2 = p[e]; i2 = e; }
        }
        const float gs = 1.f / (v1 + v2);
        gates[n * 2 + 0] = v1 * gs;  gates[n * 2 + 1] = v2 * gs;
        tidx[n * 2 + 0]  = i1;       tidx[n * 2 + 1]  = i2;
    }
}

// ---------------------------------------------------------------------------
// Single-block scan: exact slot-order ranks, capacity drop, tok_buf, aux loss.
// ---------------------------------------------------------------------------
__global__ __launch_bounds__(256) void k_scan(
    const int* __restrict__ tidx, const float* __restrict__ probs,
    int* __restrict__ slot, int* __restrict__ tok, float* __restrict__ d_aux)
{
    __shared__ int   lcnt[256][NE];
    __shared__ float ps[256][NE];
    const int t = threadIdx.x;

    for (int i = t; i < NE * CAPE; i += 256) tok[i] = 0;

    int c8[NE];
#pragma unroll
    for (int e = 0; e < NE; ++e) c8[e] = 0;
    const int per  = NSLOT / 256;   // 64
    const int base = t * per;
    for (int s = 0; s < per; ++s) c8[tidx[base + s]]++;
#pragma unroll
    for (int e = 0; e < NE; ++e) lcnt[t][e] = c8[e];

    float f8[NE];
#pragma unroll
    for (int e = 0; e < NE; ++e) f8[e] = 0.f;
    for (int n = t; n < NTOK; n += 256) {
        const float4 a = *(const float4*)(probs + (size_t)n * NE);
        const float4 b = *(const float4*)(probs + (size_t)n * NE + 4);
        f8[0] += a.x; f8[1] += a.y; f8[2] += a.z; f8[3] += a.w;
        f8[4] += b.x; f8[5] += b.y; f8[6] += b.z; f8[7] += b.w;
    }
#pragma unroll
    for (int e = 0; e < NE; ++e) ps[t][e] = f8[e];

    __syncthreads();

    int pre[NE], tot[NE];
#pragma unroll
    for (int e = 0; e < NE; ++e) { pre[e] = 0; tot[e] = 0; }
    for (int tt = 0; tt < 256; ++tt) {
#pragma unroll
        for (int e = 0; e < NE; ++e) {
            const int v = lcnt[tt][e];
            tot[e] += v;
            if (tt < t) pre[e] += v;
        }
    }
    for (int s = 0; s < per; ++s) {
        const int sg = base + s;
        const int e  = tidx[sg];
        const int p  = pre[e]++;
        if (p < CAPE) { slot[sg] = e * CAPE + p; tok[e * CAPE + p] = sg >> 1; }
        else          { slot[sg] = -1; }
    }
    if (t == 0) {
        float imp[NE], isum = 0.f, ld[NE], lsum = 0.f;
#pragma unroll
        for (int e = 0; e < NE; ++e) {
            float v = 0.f;
            for (int tt = 0; tt < 256; ++tt) v += ps[tt][e];
            imp[e] = v; isum += v;
        }
#pragma unroll
        for (int e = 0; e < NE; ++e) { ld[e] = fminf((float)tot[e], (float)CAPE); lsum += ld[e]; }
        float aux = 0.f;
#pragma unroll
        for (int e = 0; e < NE; ++e) aux += (imp[e] / isum) * (ld[e] / lsum);
        *d_aux = aux * (float)(NE * NE);
    }
}

// ---------------------------------------------------------------------------
// Gather tokens into dense per-expert buffers, fp32 -> bf16.
// ---------------------------------------------------------------------------
__global__ __launch_bounds__(256) void k_gather(
    const float* __restrict__ x, const int* __restrict__ tok,
    __bf16* __restrict__ inp)
{
    const int row = blockIdx.x;
    const int t   = threadIdx.x;
    const int tk  = tok[row];
    const float4 v = ((const float4*)(x + (size_t)tk * CDIM))[t];
    bf16x4 o;
    o[0] = (__bf16)v.x; o[1] = (__bf16)v.y; o[2] = (__bf16)v.z; o[3] = (__bf16)v.w;
    *(bf16x4*)(inp + (size_t)row * CDIM + t * 4) = o;
}

// ---------------------------------------------------------------------------
// 256x128 8-wave MFMA GEMM, BK=32, TRIPLE-buffered 72KiB LDS -> 2 blocks/CU.
//   Wave-tile 64x64 (acc[4][4] = 64 VGPR); __launch_bounds__(512,4) caps 128
//   VGPR so 16 waves/CU co-reside; cross-block TLP fills vmcnt/barrier stalls.
//   Per K-tile: {vmcnt(3); barrier; 8x ds_read_b128; STAGE(T+2) (3x
//   global_load_lds, clamped at tail for uniform counts); lgkm(0); setprio(1)
//   16 MFMA setprio(0)}. WVM-before-barrier makes per-wave vmcnt a block-wide
//   guarantee. 64B LDS rows -> column reads are a free 2-way bank alias, no
//   swizzle needed. Buffers rotate 0/24576/49152.
// ---------------------------------------------------------------------------
#define MFMA_BF16 __builtin_amdgcn_mfma_f32_16x16x32_bf16
#define DSR_I(dst, addr, IMM) \
    asm volatile("ds_read_b128 %0, %1 offset:" #IMM : "=v"(dst) : "v"(addr))
#define DSR(dst, addr, IMM) DSR_I(dst, addr, IMM)
#define SB0()  __builtin_amdgcn_sched_barrier(0)

template <bool GELU>
__global__ __launch_bounds__(512, 4) void k_gemmT(
    const __bf16* __restrict__ Aall, const __bf16* __restrict__ Ball,
    const float* __restrict__ biasAll, __bf16* __restrict__ Call,
    int Ktot, int Ntot, int NBN, int mtPerE)
{
    __shared__ char lds[73728];            // 3 x (A 16KB @0 + B 8KB @16384)

    const int NK  = Ktot >> 5;             // BK = 32
    const int cpx = gridDim.x >> 3;        // grid % 8 == 0 by caller
    const int id  = blockIdx.x;
    const int sid = (id & 7) * cpx + (id >> 3);   // bijective XCD swizzle
    const int bm  = sid / NBN, bn = sid % NBN;
    const int e   = bm / mtPerE;

    const size_t row0 = (size_t)bm * 256;
    const int    col0 = bn * 128;

    const int tid = threadIdx.x;
    const int w   = tid >> 6, l = tid & 63;
    const int wr  = w >> 1, wc = w & 1;    // 4M x 2N wave grid, 64x64/wave
    const int lr  = l & 15, hi = l >> 4;

    // staging: thread t covers row t>>2 (+128 for A's 2nd instr), k-chunk t&3
    const int srow = tid >> 2;                          // 0..127
    const int kc   = (tid & 3) * 8;                     // k elems
    const __bf16* pA = Aall + (row0 + srow) * (size_t)Ktot + kc;
    const __bf16* pB = Ball + ((size_t)e * Ntot + col0 + srow) * (size_t)Ktot + kc;
    const size_t rstepA = (size_t)128 * Ktot;
    const unsigned L0 = (unsigned)(size_t)(LAS char*)lds;
    const unsigned dA = L0 + w * 1024;                  // HW adds lane*16
    const unsigned dB = L0 + 16384 + w * 1024;

    auto STAGE = [&](unsigned bo, int kt) {
        const __bf16* ga = pA + (size_t)kt * 32;
        const __bf16* gb = pB + (size_t)kt * 32;
        __builtin_amdgcn_global_load_lds((const GAS void*)ga,
            (LAS void*)(size_t)(dA + bo), 16, 0, 0);
        __builtin_amdgcn_global_load_lds((const GAS void*)(ga + rstepA),
            (LAS void*)(size_t)(dA + bo + 8192), 16, 0, 0);
        __builtin_amdgcn_global_load_lds((const GAS void*)gb,
            (LAS void*)(size_t)(dB + bo), 16, 0, 0);
    };

    // fragment read bases: row*64B + hi*16; m/n advance 16 rows = 1024B imm
    const unsigned foff  = (unsigned)(lr * 64 + hi * 16);
    const unsigned vaB = L0 + (unsigned)(wr * 4096) + foff;
    const unsigned vbB = L0 + 16384 + (unsigned)(wc * 4096) + foff;

    // prologue: tiles 0,1 into bufs 0,1
    STAGE(0, 0);
    STAGE(24576, (NK > 1) ? 1 : 0);

    f32x4 acc[4][4] = {};
    bf16x8 fa[4], fb[4];

    unsigned cur = 0, stg = 49152;
    for (int T = 0; T < NK; ++T) {
        asm volatile("s_waitcnt vmcnt(3)" ::: "memory");   // tile T landed
        __builtin_amdgcn_s_barrier();                      // ..for ALL waves
        SB0();
        const unsigned va = vaB + cur, vb = vbB + cur;
        DSR(fa[0], va, 0); DSR(fa[1], va, 1024);
        DSR(fa[2], va, 2048); DSR(fa[3], va, 3072);
        DSR(fb[0], vb, 0); DSR(fb[1], vb, 1024);
        DSR(fb[2], vb, 2048); DSR(fb[3], vb, 3072);
        int kt = T + 2; if (kt > NK - 1) kt = NK - 1;      // uniform counts
        STAGE(stg, kt);
        asm volatile("s_waitcnt lgkmcnt(0)" ::: "memory");
        SB0();
        __builtin_amdgcn_s_setprio(1);
#pragma unroll
        for (int n = 0; n < 4; ++n)
#pragma unroll
            for (int m = 0; m < 4; ++m)
                acc[m][n] = MFMA_BF16(fb[n], fa[m], acc[m][n], 0, 0, 0);
        __builtin_amdgcn_s_setprio(0);
        SB0();
        cur = (cur == 49152u) ? 0u : cur + 24576u;
        stg = (stg == 49152u) ? 0u : stg + 24576u;
    }

    // ---- epilogue: row = m*16 + lr, col = n*16 + hi*4 + i (bf16x4 stores) ----
    const size_t crow0 = row0 + (size_t)wr * 64;
    const int    ccol0 = col0 + wc * 64;
#pragma unroll
    for (int n = 0; n < 4; ++n) {
        float bbv[4] = {0.f, 0.f, 0.f, 0.f};
        if (GELU) {
            const float4 b4 = *(const float4*)(biasAll + (size_t)e * Ntot
                                               + ccol0 + n * 16 + hi * 4);
            bbv[0] = b4.x; bbv[1] = b4.y; bbv[2] = b4.z; bbv[3] = b4.w;
        }
#pragma unroll
        for (int m = 0; m < 4; ++m) {
            const f32x4 v = acc[m][n];
            bf16x4 o;
#pragma unroll
            for (int i = 0; i < 4; ++i) {
                float t = v[i];
                if (GELU) {
                    t += bbv[i];
                    const float u  = 0.7978845608028654f * (t + 0.044715f * t * t * t);
                    const float ex = __expf(2.f * u);
                    t = t * (1.f - 1.f / (ex + 1.f));   // 0.5t(1+tanh u)
                }
                o[i] = (__bf16)t;
            }
            *(bf16x4*)(Call + (crow0 + m * 16 + lr) * (size_t)Ntot
                       + ccol0 + n * 16 + hi * 4) = o;
        }
    }
}

// ---------------------------------------------------------------------------
// Combine: y[n][c] = sum_k gate * (out[slot][c] + b2[e][c]); writes all of y.
// ---------------------------------------------------------------------------
__global__ __launch_bounds__(256) void k_combine(
    const __bf16* __restrict__ outb, const int* __restrict__ slot,
    const float* __restrict__ gates, const int* __restrict__ tidx,
    const float* __restrict__ b2, float* __restrict__ y)
{
    const int n = blockIdx.x;
    const int t = threadIdx.x;
    const int c = t * 4;
    float r0 = 0.f, r1 = 0.f, r2 = 0.f, r3 = 0.f;
#pragma unroll
    for (int k = 0; k < KTOP; ++k) {
        const int s = slot[n * 2 + k];
        if (s < 0) continue;
        const float g = gates[n * 2 + k];
        const int   e = tidx[n * 2 + k];
        const bf16x4 v = *(const bf16x4*)(outb + (size_t)s * CDIM + c);
        const float4 bb = *(const float4*)(b2 + (size_t)e * CDIM + c);
        r0 += g * ((float)v[0] + bb.x);
        r1 += g * ((float)v[1] + bb.y);
        r2 += g * ((float)v[2] + bb.z);
        r3 += g * ((float)v[3] + bb.w);
    }
    float4 o = make_float4(r0, r1, r2, r3);
    *(float4*)(y + (size_t)n * CDIM + c) = o;
}

// ---------------------------------------------------------------------------
extern "C" void kernel_launch(void* const* d_in, const int* in_sizes, int n_in,
                              void* d_out, int out_size, void* d_ws, size_t ws_size,
                              hipStream_t stream)
{
    const float* x  = (const float*)d_in[0];
    const float* rw = (const float*)d_in[1];
    const float* rb = (const float*)d_in[2];
    const float* w1 = (const float*)d_in[3];
    const float* b1 = (const float*)d_in[4];
    const float* w2 = (const float*)d_in[5];
    const float* b2 = (const float*)d_in[6];
    float* y = (float*)d_out;

    char* ws = (char*)d_ws;
    size_t off = 0;
    auto alloc = [&](size_t bytes) -> void* {
        void* p = ws + off;
        off = (off + bytes + 255) & ~(size_t)255;
        return p;
    };
    __bf16* w1t  = (__bf16*)alloc((size_t)NE * CDIM * HDIM * 2);   // [E][H][C]
    __bf16* w2t  = (__bf16*)alloc((size_t)NE * CDIM * HDIM * 2);   // [E][C][H]
    __bf16* inp  = (__bf16*)alloc((size_t)NE * CAPE * CDIM * 2);   // [E*cap][C]
    __bf16* hbuf = (__bf16*)alloc((size_t)NE * CAPE * HDIM * 2);   // [E*cap][H]
    __bf16* outb = (__bf16*)alloc((size_t)NE * CAPE * CDIM * 2);   // [E*cap][C]
    float*  probs = (float*)alloc((size_t)NTOK * NE * 4);
    float*  gates = (float*)alloc((size_t)NTOK * 2 * 4);
    int*    tidx  = (int*)alloc((size_t)NTOK * 2 * 4);
    int*    slot  = (int*)alloc((size_t)NTOK * 2 * 4);
    int*    tok   = (int*)alloc((size_t)NE * CAPE * 4);

    // 1. weight conversion (transposed to B^T layout, bf16)
    k_transpose_bf16<<<dim3(HDIM / 32, CDIM / 32, NE), 256, 0, stream>>>(
        w1, w1t, CDIM, HDIM);
    k_transpose_bf16<<<dim3(CDIM / 32, HDIM / 32, NE), 256, 0, stream>>>(
        w2, w2t, HDIM, CDIM);

    // 2. router
    k_router<<<NTOK / 4, 256, 0, stream>>>(x, rw, rb, probs, gates, tidx);

    // 3. dispatch scan + aux loss (single block, exact FCFS order)
    k_scan<<<1, 256, 0, stream>>>(tidx, probs, slot, tok, y + (size_t)NTOK * CDIM);

    // 4. gather expert inputs (bf16)
    k_gather<<<NE * CAPE, 256, 0, stream>>>(x, tok, inp);

    // 5. expert FFN — 256x128-tile BK=32 triple-buffered GEMMs, 2 blocks/CU
    //    GEMM1: 40 m-tiles x 32 n-tiles = 1280 blocks
    k_gemmT<true><<<dim3((NE * CAPE / 256) * (HDIM / 128)), 512, 0, stream>>>(
        inp, w1t, b1, hbuf, CDIM, HDIM, HDIM / 128, CAPE / 256);
    //    GEMM2: 40 x 8 = 320 blocks
    k_gemmT<false><<<dim3((NE * CAPE / 256) * (CDIM / 128)), 512, 0, stream>>>(
        hbuf, w2t, nullptr, outb, HDIM, CDIM, CDIM / 128, CAPE / 256);

    // 6. combine back to tokens (+aux already written by scan)
    k_combine<<<NTOK, 256, 0, stream>>>(outb, slot, gates, tidx, b2, y);
}

// Round 9
// 413.326 us; speedup vs baseline: 1.0267x; 1.0267x over previous
//
#include <hip/hip_runtime.h>
#include <hip/hip_bf16.h>
#include <math.h>

#define NE    8
#define KTOP  2
#define CDIM  1024
#define HDIM  4096
#define NTOK  8192
#define CAPE  1280
#define NSLOT (NTOK * KTOP)

typedef __bf16 bf16x8 __attribute__((ext_vector_type(8)));
typedef __bf16 bf16x4 __attribute__((ext_vector_type(4)));
typedef __bf16 bf16x2 __attribute__((ext_vector_type(2)));
typedef float  f32x4  __attribute__((ext_vector_type(4)));

#define GAS __attribute__((address_space(1)))
#define LAS __attribute__((address_space(3)))

// ---------------------------------------------------------------------------
// Transposing fp32 -> bf16 weight conversion: src [E][R][Cc] -> dst [E][Cc][R]
// 64x64 tile, per-thread 4x4 register blocklet, bf16 LDS staging, bf16x8
// coalesced stores (128B segments). Race-free: single sync, one-shot LDS use.
// ---------------------------------------------------------------------------
__global__ __launch_bounds__(256) void k_transpose_bf16(
    const float* __restrict__ src, __bf16* __restrict__ dst, int R, int Cc)
{
    __shared__ __bf16 T[64][72];           // 72 pad: 144B rows, 16B-aligned
    const int e  = blockIdx.z;
    const int cb = blockIdx.x * 64;
    const int rb = blockIdx.y * 64;
    const int t  = threadIdx.x;
    const int bx = t & 15, by = t >> 4;

    const float* s = src + (size_t)e * R * Cc
                   + (size_t)(rb + by * 4) * Cc + cb + bx * 4;
    float4 m[4];
#pragma unroll
    for (int i = 0; i < 4; ++i)
        m[i] = *(const float4*)(s + (size_t)i * Cc);
#pragma unroll
    for (int j = 0; j < 4; ++j) {
        bf16x4 v;
        v[0] = (__bf16)((&m[0].x)[j]);
        v[1] = (__bf16)((&m[1].x)[j]);
        v[2] = (__bf16)((&m[2].x)[j]);
        v[3] = (__bf16)((&m[3].x)[j]);
        *(bf16x4*)&T[bx * 4 + j][by * 4] = v;   // T[c][r] = src[r][c]
    }
    __syncthreads();
    const int oc = t >> 2, rc = (t & 3) * 16;
    __bf16* d = dst + (size_t)e * R * Cc + (size_t)(cb + oc) * R + rb + rc;
    *(bf16x8*)d       = *(const bf16x8*)&T[oc][rc];
    *(bf16x8*)(d + 8) = *(const bf16x8*)&T[oc][rc + 8];
}

// ---------------------------------------------------------------------------
// Router: fp32 logits -> softmax -> top2 -> normalized gates. 1 wave = 1 token.
// ---------------------------------------------------------------------------
__global__ __launch_bounds__(256) void k_router(
    const float* __restrict__ x, const float* __restrict__ rw,
    const float* __restrict__ rb, float* __restrict__ probs,
    float* __restrict__ gates, int* __restrict__ tidx)
{
    __shared__ float rws[NE * CDIM];
    const int tid = threadIdx.x;
    for (int i = tid; i < NE * CDIM / 4; i += 256)
        ((float4*)rws)[i] = ((const float4*)rw)[i];
    __syncthreads();

    const int wave = tid >> 6, lane = tid & 63;
    const int n = blockIdx.x * 4 + wave;
    const float* xr = x + (size_t)n * CDIM;

    float acc[NE];
#pragma unroll
    for (int e = 0; e < NE; ++e) acc[e] = 0.f;
    for (int j = 0; j < CDIM / 64; ++j) {
        const float xv = xr[j * 64 + lane];
#pragma unroll
        for (int e = 0; e < NE; ++e) acc[e] += xv * rws[e * CDIM + j * 64 + lane];
    }
#pragma unroll
    for (int off = 32; off > 0; off >>= 1) {
#pragma unroll
        for (int e = 0; e < NE; ++e) acc[e] += __shfl_down(acc[e], off);
    }
    if (lane == 0) {
        float mx = -1e30f;
#pragma unroll
        for (int e = 0; e < NE; ++e) { acc[e] += rb[e]; mx = fmaxf(mx, acc[e]); }
        float p[NE], s = 0.f;
#pragma unroll
        for (int e = 0; e < NE; ++e) { p[e] = expf(acc[e] - mx); s += p[e]; }
        const float inv = 1.f / s;
#pragma unroll
        for (int e = 0; e < NE; ++e) { p[e] *= inv; probs[(size_t)n * NE + e] = p[e]; }
        int   i1 = 0;  float v1 = p[0];
        int   i2 = -1; float v2 = -1.f;
#pragma unroll
        for (int e = 1; e < NE; ++e) {
            if (p[e] > v1)      { v2 = v1; i2 = i1; v1 = p[e]; i1 = e; }
            else if (p[e] > v2) { v2 = p[e]; i2 = e; }
        }
        const float gs = 1.f / (v1 + v2);
        gates[n * 2 + 0] = v1 * gs;  gates[n * 2 + 1] = v2 * gs;
        tidx[n * 2 + 0]  = i1;       tidx[n * 2 + 1]  = i2;
    }
}

// ---------------------------------------------------------------------------
// Single-block scan: exact slot-order ranks, capacity drop, tok_buf, aux loss.
// ---------------------------------------------------------------------------
__global__ __launch_bounds__(256) void k_scan(
    const int* __restrict__ tidx, const float* __restrict__ probs,
    int* __restrict__ slot, int* __restrict__ tok, float* __restrict__ d_aux)
{
    __shared__ int   lcnt[256][NE];
    __shared__ float ps[256][NE];
    const int t = threadIdx.x;

    for (int i = t; i < NE * CAPE; i += 256) tok[i] = 0;

    int c8[NE];
#pragma unroll
    for (int e = 0; e < NE; ++e) c8[e] = 0;
    const int per  = NSLOT / 256;   // 64
    const int base = t * per;
    for (int s = 0; s < per; ++s) c8[tidx[base + s]]++;
#pragma unroll
    for (int e = 0; e < NE; ++e) lcnt[t][e] = c8[e];

    float f8[NE];
#pragma unroll
    for (int e = 0; e < NE; ++e) f8[e] = 0.f;
    for (int n = t; n < NTOK; n += 256) {
        const float4 a = *(const float4*)(probs + (size_t)n * NE);
        const float4 b = *(const float4*)(probs + (size_t)n * NE + 4);
        f8[0] += a.x; f8[1] += a.y; f8[2] += a.z; f8[3] += a.w;
        f8[4] += b.x; f8[5] += b.y; f8[6] += b.z; f8[7] += b.w;
    }
#pragma unroll
    for (int e = 0; e < NE; ++e) ps[t][e] = f8[e];

    __syncthreads();

    int pre[NE], tot[NE];
#pragma unroll
    for (int e = 0; e < NE; ++e) { pre[e] = 0; tot[e] = 0; }
    for (int tt = 0; tt < 256; ++tt) {
#pragma unroll
        for (int e = 0; e < NE; ++e) {
            const int v = lcnt[tt][e];
            tot[e] += v;
            if (tt < t) pre[e] += v;
        }
    }
    for (int s = 0; s < per; ++s) {
        const int sg = base + s;
        const int e  = tidx[sg];
        const int p  = pre[e]++;
        if (p < CAPE) { slot[sg] = e * CAPE + p; tok[e * CAPE + p] = sg >> 1; }
        else          { slot[sg] = -1; }
    }
    if (t == 0) {
        float imp[NE], isum = 0.f, ld[NE], lsum = 0.f;
#pragma unroll
        for (int e = 0; e < NE; ++e) {
            float v = 0.f;
            for (int tt = 0; tt < 256; ++tt) v += ps[tt][e];
            imp[e] = v; isum += v;
        }
#pragma unroll
        for (int e = 0; e < NE; ++e) { ld[e] = fminf((float)tot[e], (float)CAPE); lsum += ld[e]; }
        float aux = 0.f;
#pragma unroll
        for (int e = 0; e < NE; ++e) aux += (imp[e] / isum) * (ld[e] / lsum);
        *d_aux = aux * (float)(NE * NE);
    }
}

// ---------------------------------------------------------------------------
// Gather tokens into dense per-expert buffers, fp32 -> bf16.
// ---------------------------------------------------------------------------
__global__ __launch_bounds__(256) void k_gather(
    const float* __restrict__ x, const int* __restrict__ tok,
    __bf16* __restrict__ inp)
{
    const int row = blockIdx.x;
    const int t   = threadIdx.x;
    const int tk  = tok[row];
    const float4 v = ((const float4*)(x + (size_t)tk * CDIM))[t];
    bf16x4 o;
    o[0] = (__bf16)v.x; o[1] = (__bf16)v.y; o[2] = (__bf16)v.z; o[3] = (__bf16)v.w;
    *(bf16x4*)(inp + (size_t)row * CDIM + t * 4) = o;
}

// ---------------------------------------------------------------------------
// 256x256 8-wave MFMA GEMM — m201 8-phase structure (replay-proven in R6).
// ---------------------------------------------------------------------------
#define MFMA_BF16 __builtin_amdgcn_mfma_f32_16x16x32_bf16
#define DSR_I(dst, addr, IMM) \
    asm volatile("ds_read_b128 %0, %1 offset:" #IMM : "=v"(dst) : "v"(addr))
#define DSR(dst, addr, IMM) DSR_I(dst, addr, IMM)
#define WVM4() asm volatile("s_waitcnt vmcnt(4)" ::: "memory")
#define SB0()  __builtin_amdgcn_sched_barrier(0)

#define PH(RDB, OA0, OA1, MB, VA0, VA1, VB0, VB1, STG, VMW)                   \
    {                                                                         \
        if (RDB) {                                                            \
            DSR(fb[0][0], VB0, 0);    DSR(fb[0][1], VB1, 0);                  \
            DSR(fb[1][0], VB0, 2048); DSR(fb[1][1], VB1, 2048);               \
            DSR(fb[2][0], VB0, 4096); DSR(fb[2][1], VB1, 4096);               \
            DSR(fb[3][0], VB0, 6144); DSR(fb[3][1], VB1, 6144);               \
        }                                                                     \
        DSR(fa[0][0], VA0, OA0); DSR(fa[0][1], VA1, OA0);                     \
        DSR(fa[1][0], VA0, OA1); DSR(fa[1][1], VA1, OA1);                     \
        STG;                                                                  \
        if (RDB) { asm volatile("s_waitcnt lgkmcnt(8)" ::: "memory"); }       \
        __builtin_amdgcn_s_barrier();                                         \
        asm volatile("s_waitcnt lgkmcnt(0)" ::: "memory");                    \
        SB0();                                                                \
        __builtin_amdgcn_s_setprio(1);                                        \
        _Pragma("unroll")                                                     \
        for (int n = 0; n < 4; ++n) {                                         \
            acc[MB][n]   = MFMA_BF16(fb[n][0], fa[0][0], acc[MB][n], 0,0,0);  \
            acc[MB][n]   = MFMA_BF16(fb[n][1], fa[0][1], acc[MB][n], 0,0,0);  \
            acc[MB+1][n] = MFMA_BF16(fb[n][0], fa[1][0], acc[MB+1][n],0,0,0); \
            acc[MB+1][n] = MFMA_BF16(fb[n][1], fa[1][1], acc[MB+1][n],0,0,0); \
        }                                                                     \
        __builtin_amdgcn_s_setprio(0);                                        \
        VMW;                                                                  \
        __builtin_amdgcn_s_barrier();                                        \
        SB0();                                                                \
    }

template <bool GELU>
__global__ __launch_bounds__(512, 2) void k_gemm8(
    const __bf16* __restrict__ Aall, const __bf16* __restrict__ Ball,
    const float* __restrict__ biasAll, __bf16* __restrict__ Call,
    int Ktot, int Ntot, int NBN, int mtPerE)
{
    __shared__ char lds[131072];   // A: [buf][half] @0; B: @65536

    const int NK  = Ktot >> 6;
    const int NI  = NK >> 1;
    const int cpx = gridDim.x >> 3;                 // grid % 8 == 0 by caller
    const int id  = blockIdx.x;
    const int sid = (id & 7) * cpx + (id >> 3);     // bijective XCD swizzle
    const int bm  = sid / NBN, bn = sid % NBN;
    const int e   = bm / mtPerE;

    const size_t row0 = (size_t)bm * 256;
    const int    col0 = bn * 256;

    const int tid = threadIdx.x;
    const int w   = tid >> 6, l = tid & 63;
    const int wr  = w >> 2, wc = w & 3;             // 2M x 4N wave grid
    const int lr  = l & 15, hi = l >> 4;

    // staging: thread covers rloc = g*64 + (tid>>3), k-chunk tid&7, pre-swizzled
    const int srow = tid >> 3;                              // 0..63
    const int kf   = ((tid & 7) ^ (srow & 7)) << 3;         // swizzled k elems
    const __bf16* pA = Aall + (row0 + srow) * (size_t)Ktot + kf;
    const __bf16* pB = Ball + ((size_t)e * Ntot + col0 + srow) * (size_t)Ktot + kf;
    const unsigned L0 = (unsigned)(size_t)(LAS char*)lds;

    const unsigned sA00 = L0 +          w * 1024;
    const unsigned sA01 = sA00 + 16384;
    const unsigned sA10 = sA00 + 32768;
    const unsigned sA11 = sA00 + 49152;
    const unsigned sB00 = sA00 + 65536;
    const unsigned sB01 = sB00 + 16384;
    const unsigned sB10 = sB00 + 32768;
    const unsigned sB11 = sB00 + 49152;

    auto SH_A = [&](unsigned dbase, int half, int kt) {
        const __bf16* g = pA + (size_t)(half * 128) * Ktot + (size_t)kt * 64;
#pragma unroll
        for (int gg = 0; gg < 2; ++gg)
            __builtin_amdgcn_global_load_lds(
                (const GAS void*)(g + (size_t)gg * 64 * Ktot),
                (LAS void*)(size_t)(dbase + gg * 8192), 16, 0, 0);
    };
    auto SH_B = [&](unsigned dbase, int half, int kt) {
        const __bf16* g = pB + (size_t)(half * 128) * Ktot + (size_t)kt * 64;
#pragma unroll
        for (int gg = 0; gg < 2; ++gg)
            __builtin_amdgcn_global_load_lds(
                (const GAS void*)(g + (size_t)gg * 64 * Ktot),
                (LAS void*)(size_t)(dbase + gg * 8192), 16, 0, 0);
    };

    const unsigned swz = (l & 7) << 4;
    const unsigned kb0 = ((unsigned)(hi << 4)) ^ swz;
    const unsigned kb1 = ((unsigned)(64 + (hi << 4))) ^ swz;
    const unsigned vA00 = L0 + (unsigned)(wr * 16384 + lr * 128) + kb0;
    const unsigned vA01 = L0 + (unsigned)(wr * 16384 + lr * 128) + kb1;
    const unsigned vA10 = vA00 + 32768, vA11 = vA01 + 32768;
    const unsigned vBb  = L0 + 65536
        + (unsigned)((wc >> 1) * 16384 + ((wc & 1) * 64 + lr) * 128);
    const unsigned vB00 = vBb + kb0, vB01 = vBb + kb1;
    const unsigned vB10 = vB00 + 32768, vB11 = vB01 + 32768;

    // prologue: B0(0), A0(0), B1(1) staged; retire B0,A0; barrier
    SH_B(sB00, 0, 0); SH_B(sB01, 1, 0);
    SH_A(sA00, 0, 0); SH_A(sA01, 1, 0);
    SH_B(sB10, 0, 1); SH_B(sB11, 1, 1);
    WVM4();
    __builtin_amdgcn_s_barrier();
    SB0();

    f32x4 acc[8][4] = {};
    bf16x8 fa[2][2], fb[4][2];

    for (int i = 0; i < NI; ++i) {
        const int t1 = 2 * i + 1;
        const int t2 = (2 * i + 2 < NK) ? 2 * i + 2 : NK - 1;
        const int t3 = (2 * i + 3 < NK) ? 2 * i + 3 : NK - 1;
        // tile 2i (buf0), phases 1-4
        PH(1, 0,     2048,  0, vA00, vA01, vB00, vB01, SH_A(sA10, 0, t1), (void)0)
        PH(0, 4096,  6144,  2, vA00, vA01, vB00, vB01, SH_A(sA11, 1, t1), (void)0)
        PH(0, 8192,  10240, 4, vA00, vA01, vB00, vB01, SH_B(sB00, 0, t2), (void)0)
        PH(0, 12288, 14336, 6, vA00, vA01, vB00, vB01, SH_B(sB01, 1, t2), WVM4())
        // tile 2i+1 (buf1), phases 5-8
        PH(1, 0,     2048,  0, vA10, vA11, vB10, vB11, SH_A(sA00, 0, t2), (void)0)
        PH(0, 4096,  6144,  2, vA10, vA11, vB10, vB11, SH_A(sA01, 1, t2), (void)0)
        PH(0, 8192,  10240, 4, vA10, vA11, vB10, vB11, SH_B(sB10, 0, t3), (void)0)
        PH(0, 12288, 14336, 6, vA10, vA11, vB10, vB11, SH_B(sB11, 1, t3), WVM4())
    }

    // epilogue: row = m*16 + lr, col = n*16 + hi*4 + i (bf16x4 stores)
    const size_t crow0 = row0 + (size_t)wr * 128;
    const int    ccol0 = col0 + wc * 64;
#pragma unroll
    for (int n = 0; n < 4; ++n) {
        float bbv[4] = {0.f, 0.f, 0.f, 0.f};
        if (GELU) {
            const float4 b4 = *(const float4*)(biasAll + (size_t)e * Ntot
                                               + ccol0 + n * 16 + hi * 4);
            bbv[0] = b4.x; bbv[1] = b4.y; bbv[2] = b4.z; bbv[3] = b4.w;
        }
#pragma unroll
        for (int m = 0; m < 8; ++m) {
            const f32x4 v = acc[m][n];
            bf16x4 o;
#pragma unroll
            for (int i = 0; i < 4; ++i) {
                float t = v[i];
                if (GELU) {
                    t += bbv[i];
                    const float u  = 0.7978845608028654f * (t + 0.044715f * t * t * t);
                    const float ex = __expf(2.f * u);
                    t = t * (1.f - 1.f / (ex + 1.f));   // 0.5t(1+tanh u)
                }
                o[i] = (__bf16)t;
            }
            *(bf16x4*)(Call + (crow0 + m * 16 + lr) * (size_t)Ntot
                       + ccol0 + n * 16 + hi * 4) = o;
        }
    }
}

// ---------------------------------------------------------------------------
// Combine: y[n][c] = sum_k gate * (out[slot][c] + b2[e][c]); writes all of y.
// ---------------------------------------------------------------------------
__global__ __launch_bounds__(256) void k_combine(
    const __bf16* __restrict__ outb, const int* __restrict__ slot,
    const float* __restrict__ gates, const int* __restrict__ tidx,
    const float* __restrict__ b2, float* __restrict__ y)
{
    const int n = blockIdx.x;
    const int t = threadIdx.x;
    const int c = t * 4;
    float r0 = 0.f, r1 = 0.f, r2 = 0.f, r3 = 0.f;
#pragma unroll
    for (int k = 0; k < KTOP; ++k) {
        const int s = slot[n * 2 + k];
        if (s < 0) continue;
        const float g = gates[n * 2 + k];
        const int   e = tidx[n * 2 + k];
        const bf16x4 v = *(const bf16x4*)(outb + (size_t)s * CDIM + c);
        const float4 bb = *(const float4*)(b2 + (size_t)e * CDIM + c);
        r0 += g * ((float)v[0] + bb.x);
        r1 += g * ((float)v[1] + bb.y);
        r2 += g * ((float)v[2] + bb.z);
        r3 += g * ((float)v[3] + bb.w);
    }
    float4 o = make_float4(r0, r1, r2, r3);
    *(float4*)(y + (size_t)n * CDIM + c) = o;
}

// ---------------------------------------------------------------------------
extern "C" void kernel_launch(void* const* d_in, const int* in_sizes, int n_in,
                              void* d_out, int out_size, void* d_ws, size_t ws_size,
                              hipStream_t stream)
{
    const float* x  = (const float*)d_in[0];
    const float* rw = (const float*)d_in[1];
    const float* rb = (const float*)d_in[2];
    const float* w1 = (const float*)d_in[3];
    const float* b1 = (const float*)d_in[4];
    const float* w2 = (const float*)d_in[5];
    const float* b2 = (const float*)d_in[6];
    float* y = (float*)d_out;

    char* ws = (char*)d_ws;
    size_t off = 0;
    auto alloc = [&](size_t bytes) -> void* {
        void* p = ws + off;
        off = (off + bytes + 255) & ~(size_t)255;
        return p;
    };
    __bf16* w1t  = (__bf16*)alloc((size_t)NE * CDIM * HDIM * 2);   // [E][H][C]
    __bf16* w2t  = (__bf16*)alloc((size_t)NE * CDIM * HDIM * 2);   // [E][C][H]
    __bf16* inp  = (__bf16*)alloc((size_t)NE * CAPE * CDIM * 2);   // [E*cap][C]
    __bf16* hbuf = (__bf16*)alloc((size_t)NE * CAPE * HDIM * 2);   // [E*cap][H]
    __bf16* outb = (__bf16*)alloc((size_t)NE * CAPE * CDIM * 2);   // [E*cap][C]
    float*  probs = (float*)alloc((size_t)NTOK * NE * 4);
    float*  gates = (float*)alloc((size_t)NTOK * 2 * 4);
    int*    tidx  = (int*)alloc((size_t)NTOK * 2 * 4);
    int*    slot  = (int*)alloc((size_t)NTOK * 2 * 4);
    int*    tok   = (int*)alloc((size_t)NE * CAPE * 4);

    // 1. weight conversion (transposed to B^T layout, bf16) — 64x64 tiles
    k_transpose_bf16<<<dim3(HDIM / 64, CDIM / 64, NE), 256, 0, stream>>>(
        w1, w1t, CDIM, HDIM);
    k_transpose_bf16<<<dim3(CDIM / 64, HDIM / 64, NE), 256, 0, stream>>>(
        w2, w2t, HDIM, CDIM);

    // 2. router
    k_router<<<NTOK / 4, 256, 0, stream>>>(x, rw, rb, probs, gates, tidx);

    // 3. dispatch scan + aux loss (single block, exact FCFS order)
    k_scan<<<1, 256, 0, stream>>>(tidx, probs, slot, tok, y + (size_t)NTOK * CDIM);

    // 4. gather expert inputs (bf16)
    k_gather<<<NE * CAPE, 256, 0, stream>>>(x, tok, inp);

    // 5. expert FFN — 256^2 8-wave 8-phase MFMA GEMMs (replay-proven R6)
    k_gemm8<true><<<dim3((NE * CAPE / 256) * (HDIM / 256)), 512, 0, stream>>>(
        inp, w1t, b1, hbuf, CDIM, HDIM, HDIM / 256, CAPE / 256);
    k_gemm8<false><<<dim3((NE * CAPE / 256) * (CDIM / 256)), 512, 0, stream>>>(
        hbuf, w2t, nullptr, outb, HDIM, CDIM, CDIM / 256, CAPE / 256);

    // 6. combine back to tokens (+aux already written by scan)
    k_combine<<<NTOK, 256, 0, stream>>>(outb, slot, gates, tidx, b2, y);
}

// Round 10
// 381.805 us; speedup vs baseline: 1.1115x; 1.0826x over previous
//
#include <hip/hip_runtime.h>
#include <hip/hip_bf16.h>
#include <math.h>

#define NE    8
#define KTOP  2
#define CDIM  1024
#define HDIM  4096
#define NTOK  8192
#define CAPE  1280
#define NSLOT (NTOK * KTOP)

typedef __bf16 bf16x8 __attribute__((ext_vector_type(8)));
typedef __bf16 bf16x4 __attribute__((ext_vector_type(4)));
typedef __bf16 bf16x2 __attribute__((ext_vector_type(2)));
typedef float  f32x4  __attribute__((ext_vector_type(4)));

#define GAS __attribute__((address_space(1)))
#define LAS __attribute__((address_space(3)))

// ---------------------------------------------------------------------------
// Transposing fp32 -> bf16 weight conversion: src [E][R][Cc] -> dst [E][Cc][R]
// 64x64 tile, per-thread 4x4 register blocklet, bf16 LDS staging, bf16x8
// coalesced stores (128B segments).
// ---------------------------------------------------------------------------
__global__ __launch_bounds__(256) void k_transpose_bf16(
    const float* __restrict__ src, __bf16* __restrict__ dst, int R, int Cc)
{
    __shared__ __bf16 T[64][72];           // 72 pad: 144B rows, 16B-aligned
    const int e  = blockIdx.z;
    const int cb = blockIdx.x * 64;
    const int rb = blockIdx.y * 64;
    const int t  = threadIdx.x;
    const int bx = t & 15, by = t >> 4;

    const float* s = src + (size_t)e * R * Cc
                   + (size_t)(rb + by * 4) * Cc + cb + bx * 4;
    float4 m[4];
#pragma unroll
    for (int i = 0; i < 4; ++i)
        m[i] = *(const float4*)(s + (size_t)i * Cc);
#pragma unroll
    for (int j = 0; j < 4; ++j) {
        bf16x4 v;
        v[0] = (__bf16)((&m[0].x)[j]);
        v[1] = (__bf16)((&m[1].x)[j]);
        v[2] = (__bf16)((&m[2].x)[j]);
        v[3] = (__bf16)((&m[3].x)[j]);
        *(bf16x4*)&T[bx * 4 + j][by * 4] = v;   // T[c][r] = src[r][c]
    }
    __syncthreads();
    const int oc = t >> 2, rc = (t & 3) * 16;
    __bf16* d = dst + (size_t)e * R * Cc + (size_t)(cb + oc) * R + rb + rc;
    *(bf16x8*)d       = *(const bf16x8*)&T[oc][rc];
    *(bf16x8*)(d + 8) = *(const bf16x8*)&T[oc][rc + 8];
}

// ---------------------------------------------------------------------------
// Router: fp32 logits -> softmax -> top2 -> normalized gates. 1 wave = 1 token.
// ---------------------------------------------------------------------------
__global__ __launch_bounds__(256) void k_router(
    const float* __restrict__ x, const float* __restrict__ rw,
    const float* __restrict__ rb, float* __restrict__ probs,
    float* __restrict__ gates, int* __restrict__ tidx)
{
    __shared__ float rws[NE * CDIM];
    const int tid = threadIdx.x;
    for (int i = tid; i < NE * CDIM / 4; i += 256)
        ((float4*)rws)[i] = ((const float4*)rw)[i];
    __syncthreads();

    const int wave = tid >> 6, lane = tid & 63;
    const int n = blockIdx.x * 4 + wave;
    const float* xr = x + (size_t)n * CDIM;

    float acc[NE];
#pragma unroll
    for (int e = 0; e < NE; ++e) acc[e] = 0.f;
    for (int j = 0; j < CDIM / 64; ++j) {
        const float xv = xr[j * 64 + lane];
#pragma unroll
        for (int e = 0; e < NE; ++e) acc[e] += xv * rws[e * CDIM + j * 64 + lane];
    }
#pragma unroll
    for (int off = 32; off > 0; off >>= 1) {
#pragma unroll
        for (int e = 0; e < NE; ++e) acc[e] += __shfl_down(acc[e], off);
    }
    if (lane == 0) {
        float mx = -1e30f;
#pragma unroll
        for (int e = 0; e < NE; ++e) { acc[e] += rb[e]; mx = fmaxf(mx, acc[e]); }
        float p[NE], s = 0.f;
#pragma unroll
        for (int e = 0; e < NE; ++e) { p[e] = expf(acc[e] - mx); s += p[e]; }
        const float inv = 1.f / s;
#pragma unroll
        for (int e = 0; e < NE; ++e) { p[e] *= inv; probs[(size_t)n * NE + e] = p[e]; }
        int   i1 = 0;  float v1 = p[0];
        int   i2 = -1; float v2 = -1.f;
#pragma unroll
        for (int e = 1; e < NE; ++e) {
            if (p[e] > v1)      { v2 = v1; i2 = i1; v1 = p[e]; i1 = e; }
            else if (p[e] > v2) { v2 = p[e]; i2 = e; }
        }
        const float gs = 1.f / (v1 + v2);
        gates[n * 2 + 0] = v1 * gs;  gates[n * 2 + 1] = v2 * gs;
        tidx[n * 2 + 0]  = i1;       tidx[n * 2 + 1]  = i2;
    }
}

// ---------------------------------------------------------------------------
// Single-block scan — Hillis-Steele log-scan (8 steps) replaces the serial
// 256-iteration prefix; parallel tree-reduce for the probs sum.
// Semantics identical: exact FCFS slot order, capacity drop, tok_buf, aux.
// ---------------------------------------------------------------------------
__global__ __launch_bounds__(256) void k_scan(
    const int* __restrict__ tidx, const float* __restrict__ probs,
    int* __restrict__ slot, int* __restrict__ tok, float* __restrict__ d_aux)
{
    __shared__ int   lcnt[256][NE];
    __shared__ float ps[256][NE];
    const int t = threadIdx.x;

    for (int i = t; i < NE * CAPE; i += 256) tok[i] = 0;

    int c8[NE];
#pragma unroll
    for (int e = 0; e < NE; ++e) c8[e] = 0;
    const int per  = NSLOT / 256;   // 64
    const int base = t * per;
    for (int s = 0; s < per; ++s) c8[tidx[base + s]]++;
#pragma unroll
    for (int e = 0; e < NE; ++e) lcnt[t][e] = c8[e];

    float f8[NE];
#pragma unroll
    for (int e = 0; e < NE; ++e) f8[e] = 0.f;
    for (int n = t; n < NTOK; n += 256) {
        const float4 a = *(const float4*)(probs + (size_t)n * NE);
        const float4 b = *(const float4*)(probs + (size_t)n * NE + 4);
        f8[0] += a.x; f8[1] += a.y; f8[2] += a.z; f8[3] += a.w;
        f8[4] += b.x; f8[5] += b.y; f8[6] += b.z; f8[7] += b.w;
    }
#pragma unroll
    for (int e = 0; e < NE; ++e) ps[t][e] = f8[e];

    __syncthreads();

    // ---- Hillis-Steele inclusive scan across tt for 8 counters ----
    int run[NE];
#pragma unroll
    for (int e = 0; e < NE; ++e) run[e] = c8[e];
    for (int d = 1; d < 256; d <<= 1) {
        int add[NE];
#pragma unroll
        for (int e = 0; e < NE; ++e) add[e] = (t >= d) ? lcnt[t - d][e] : 0;
        __syncthreads();
#pragma unroll
        for (int e = 0; e < NE; ++e) { run[e] += add[e]; lcnt[t][e] = run[e]; }
        __syncthreads();
    }
    int pre[NE], tot[NE];
#pragma unroll
    for (int e = 0; e < NE; ++e) {
        pre[e] = run[e] - c8[e];          // exclusive prefix
        tot[e] = lcnt[255][e];            // grand total
    }

    // ---- parallel tree-reduce of ps ----
    for (int d = 128; d >= 1; d >>= 1) {
        if (t < d) {
#pragma unroll
            for (int e = 0; e < NE; ++e) ps[t][e] += ps[t + d][e];
        }
        __syncthreads();
    }

    // ---- FCFS slot assignment (order within chunk preserved) ----
    for (int s = 0; s < per; ++s) {
        const int sg = base + s;
        const int e  = tidx[sg];
        const int p  = pre[e]++;
        if (p < CAPE) { slot[sg] = e * CAPE + p; tok[e * CAPE + p] = sg >> 1; }
        else          { slot[sg] = -1; }
    }
    if (t == 0) {
        float isum = 0.f, lsum = 0.f, ld[NE];
#pragma unroll
        for (int e = 0; e < NE; ++e) isum += ps[0][e];
#pragma unroll
        for (int e = 0; e < NE; ++e) { ld[e] = fminf((float)tot[e], (float)CAPE); lsum += ld[e]; }
        float aux = 0.f;
#pragma unroll
        for (int e = 0; e < NE; ++e) aux += (ps[0][e] / isum) * (ld[e] / lsum);
        *d_aux = aux * (float)(NE * NE);
    }
}

// ---------------------------------------------------------------------------
// Gather tokens into dense per-expert buffers, fp32 -> bf16.
// ---------------------------------------------------------------------------
__global__ __launch_bounds__(256) void k_gather(
    const float* __restrict__ x, const int* __restrict__ tok,
    __bf16* __restrict__ inp)
{
    const int row = blockIdx.x;
    const int t   = threadIdx.x;
    const int tk  = tok[row];
    const float4 v = ((const float4*)(x + (size_t)tk * CDIM))[t];
    bf16x4 o;
    o[0] = (__bf16)v.x; o[1] = (__bf16)v.y; o[2] = (__bf16)v.z; o[3] = (__bf16)v.w;
    *(bf16x4*)(inp + (size_t)row * CDIM + t * 4) = o;
}

// ---------------------------------------------------------------------------
// 256x256 8-wave MFMA GEMM — m201 8-phase structure (replay-proven R6/R9).
// NEW: LDS-bounce epilogue. After the K-loop (vmcnt(0)+barrier to drain tail
// restages), GELU'd bf16 results are written to LDS ([256] rows, 520B padded
// stride), then read back row-linear (16B/lane) and stored as 512B-contiguous
// wave segments -> full-line HBM writes, no partial-sector RMW.
// ---------------------------------------------------------------------------
#define MFMA_BF16 __builtin_amdgcn_mfma_f32_16x16x32_bf16
#define DSR_I(dst, addr, IMM) \
    asm volatile("ds_read_b128 %0, %1 offset:" #IMM : "=v"(dst) : "v"(addr))
#define DSR(dst, addr, IMM) DSR_I(dst, addr, IMM)
#define WVM4() asm volatile("s_waitcnt vmcnt(4)" ::: "memory")
#define SB0()  __builtin_amdgcn_sched_barrier(0)

#define PH(RDB, OA0, OA1, MB, VA0, VA1, VB0, VB1, STG, VMW)                   \
    {                                                                         \
        if (RDB) {                                                            \
            DSR(fb[0][0], VB0, 0);    DSR(fb[0][1], VB1, 0);                  \
            DSR(fb[1][0], VB0, 2048); DSR(fb[1][1], VB1, 2048);               \
            DSR(fb[2][0], VB0, 4096); DSR(fb[2][1], VB1, 4096);               \
            DSR(fb[3][0], VB0, 6144); DSR(fb[3][1], VB1, 6144);               \
        }                                                                     \
        DSR(fa[0][0], VA0, OA0); DSR(fa[0][1], VA1, OA0);                     \
        DSR(fa[1][0], VA0, OA1); DSR(fa[1][1], VA1, OA1);                     \
        STG;                                                                  \
        if (RDB) { asm volatile("s_waitcnt lgkmcnt(8)" ::: "memory"); }       \
        __builtin_amdgcn_s_barrier();                                         \
        asm volatile("s_waitcnt lgkmcnt(0)" ::: "memory");                    \
        SB0();                                                                \
        __builtin_amdgcn_s_setprio(1);                                        \
        _Pragma("unroll")                                                     \
        for (int n = 0; n < 4; ++n) {                                         \
            acc[MB][n]   = MFMA_BF16(fb[n][0], fa[0][0], acc[MB][n], 0,0,0);  \
            acc[MB][n]   = MFMA_BF16(fb[n][1], fa[0][1], acc[MB][n], 0,0,0);  \
            acc[MB+1][n] = MFMA_BF16(fb[n][0], fa[1][0], acc[MB+1][n],0,0,0); \
            acc[MB+1][n] = MFMA_BF16(fb[n][1], fa[1][1], acc[MB+1][n],0,0,0); \
        }                                                                     \
        __builtin_amdgcn_s_setprio(0);                                        \
        VMW;                                                                  \
        __builtin_amdgcn_s_barrier();                                        \
        SB0();                                                                \
    }

template <bool GELU>
__global__ __launch_bounds__(512, 2) void k_gemm8(
    const __bf16* __restrict__ Aall, const __bf16* __restrict__ Ball,
    const float* __restrict__ biasAll, __bf16* __restrict__ Call,
    int Ktot, int Ntot, int NBN, int mtPerE)
{
    __shared__ char lds[133120];   // K-loop: A @0..64K, B @64K..128K; epilogue: [256]x520B

    const int NK  = Ktot >> 6;
    const int NI  = NK >> 1;
    const int cpx = gridDim.x >> 3;                 // grid % 8 == 0 by caller
    const int id  = blockIdx.x;
    const int sid = (id & 7) * cpx + (id >> 3);     // bijective XCD swizzle
    const int bm  = sid / NBN, bn = sid % NBN;
    const int e   = bm / mtPerE;

    const size_t row0 = (size_t)bm * 256;
    const int    col0 = bn * 256;

    const int tid = threadIdx.x;
    const int w   = tid >> 6, l = tid & 63;
    const int wr  = w >> 2, wc = w & 3;             // 2M x 4N wave grid
    const int lr  = l & 15, hi = l >> 4;

    // staging: thread covers rloc = g*64 + (tid>>3), k-chunk tid&7, pre-swizzled
    const int srow = tid >> 3;                              // 0..63
    const int kf   = ((tid & 7) ^ (srow & 7)) << 3;         // swizzled k elems
    const __bf16* pA = Aall + (row0 + srow) * (size_t)Ktot + kf;
    const __bf16* pB = Ball + ((size_t)e * Ntot + col0 + srow) * (size_t)Ktot + kf;
    const unsigned L0 = (unsigned)(size_t)(LAS char*)lds;

    const unsigned sA00 = L0 +          w * 1024;
    const unsigned sA01 = sA00 + 16384;
    const unsigned sA10 = sA00 + 32768;
    const unsigned sA11 = sA00 + 49152;
    const unsigned sB00 = sA00 + 65536;
    const unsigned sB01 = sB00 + 16384;
    const unsigned sB10 = sB00 + 32768;
    const unsigned sB11 = sB00 + 49152;

    auto SH_A = [&](unsigned dbase, int half, int kt) {
        const __bf16* g = pA + (size_t)(half * 128) * Ktot + (size_t)kt * 64;
#pragma unroll
        for (int gg = 0; gg < 2; ++gg)
            __builtin_amdgcn_global_load_lds(
                (const GAS void*)(g + (size_t)gg * 64 * Ktot),
                (LAS void*)(size_t)(dbase + gg * 8192), 16, 0, 0);
    };
    auto SH_B = [&](unsigned dbase, int half, int kt) {
        const __bf16* g = pB + (size_t)(half * 128) * Ktot + (size_t)kt * 64;
#pragma unroll
        for (int gg = 0; gg < 2; ++gg)
            __builtin_amdgcn_global_load_lds(
                (const GAS void*)(g + (size_t)gg * 64 * Ktot),
                (LAS void*)(size_t)(dbase + gg * 8192), 16, 0, 0);
    };

    const unsigned swz = (l & 7) << 4;
    const unsigned kb0 = ((unsigned)(hi << 4)) ^ swz;
    const unsigned kb1 = ((unsigned)(64 + (hi << 4))) ^ swz;
    const unsigned vA00 = L0 + (unsigned)(wr * 16384 + lr * 128) + kb0;
    const unsigned vA01 = L0 + (unsigned)(wr * 16384 + lr * 128) + kb1;
    const unsigned vA10 = vA00 + 32768, vA11 = vA01 + 32768;
    const unsigned vBb  = L0 + 65536
        + (unsigned)((wc >> 1) * 16384 + ((wc & 1) * 64 + lr) * 128);
    const unsigned vB00 = vBb + kb0, vB01 = vBb + kb1;
    const unsigned vB10 = vB00 + 32768, vB11 = vB01 + 32768;

    // prologue: B0(0), A0(0), B1(1) staged; retire B0,A0; barrier
    SH_B(sB00, 0, 0); SH_B(sB01, 1, 0);
    SH_A(sA00, 0, 0); SH_A(sA01, 1, 0);
    SH_B(sB10, 0, 1); SH_B(sB11, 1, 1);
    WVM4();
    __builtin_amdgcn_s_barrier();
    SB0();

    f32x4 acc[8][4] = {};
    bf16x8 fa[2][2], fb[4][2];

    for (int i = 0; i < NI; ++i) {
        const int t1 = 2 * i + 1;
        const int t2 = (2 * i + 2 < NK) ? 2 * i + 2 : NK - 1;
        const int t3 = (2 * i + 3 < NK) ? 2 * i + 3 : NK - 1;
        // tile 2i (buf0), phases 1-4
        PH(1, 0,     2048,  0, vA00, vA01, vB00, vB01, SH_A(sA10, 0, t1), (void)0)
        PH(0, 4096,  6144,  2, vA00, vA01, vB00, vB01, SH_A(sA11, 1, t1), (void)0)
        PH(0, 8192,  10240, 4, vA00, vA01, vB00, vB01, SH_B(sB00, 0, t2), (void)0)
        PH(0, 12288, 14336, 6, vA00, vA01, vB00, vB01, SH_B(sB01, 1, t2), WVM4())
        // tile 2i+1 (buf1), phases 5-8
        PH(1, 0,     2048,  0, vA10, vA11, vB10, vB11, SH_A(sA00, 0, t2), (void)0)
        PH(0, 4096,  6144,  2, vA10, vA11, vB10, vB11, SH_A(sA01, 1, t2), (void)0)
        PH(0, 8192,  10240, 4, vA10, vA11, vB10, vB11, SH_B(sB10, 0, t3), (void)0)
        PH(0, 12288, 14336, 6, vA10, vA11, vB10, vB11, SH_B(sB11, 1, t3), WVM4())
    }

    // ---- epilogue: drain tail staging, then LDS-bounce coalesced stores ----
    asm volatile("s_waitcnt vmcnt(0)" ::: "memory");
    __builtin_amdgcn_s_barrier();
    SB0();

    // phase 1: bias+GELU on registers, bf16 into LDS [lrow][lcol], stride 520B
    const int lrow0 = wr * 128;                 // + m*16 + lr
    const int lcol0 = wc * 64;                  // + n*16 + hi*4
#pragma unroll
    for (int n = 0; n < 4; ++n) {
        float bbv[4] = {0.f, 0.f, 0.f, 0.f};
        if (GELU) {
            const float4 b4 = *(const float4*)(biasAll + (size_t)e * Ntot
                                               + col0 + lcol0 + n * 16 + hi * 4);
            bbv[0] = b4.x; bbv[1] = b4.y; bbv[2] = b4.z; bbv[3] = b4.w;
        }
#pragma unroll
        for (int m = 0; m < 8; ++m) {
            const f32x4 v = acc[m][n];
            bf16x4 o;
#pragma unroll
            for (int i = 0; i < 4; ++i) {
                float t = v[i];
                if (GELU) {
                    t += bbv[i];
                    const float u  = 0.7978845608028654f * (t + 0.044715f * t * t * t);
                    const float ex = __expf(2.f * u);
                    t = t * (1.f - 1.f / (ex + 1.f));   // 0.5t(1+tanh u)
                }
                o[i] = (__bf16)t;
            }
            *(bf16x4*)(lds + (lrow0 + m * 16 + lr) * 520
                           + (lcol0 + n * 16 + hi * 4) * 2) = o;
        }
    }
    __builtin_amdgcn_s_barrier();

    // phase 2: row-linear readback, 512B-contiguous wave stores
    {
        const int rr0 = tid >> 5;               // 0..15
        const int cc  = (tid & 31) * 8;         // col elems, 16B per lane
#pragma unroll
        for (int it = 0; it < 16; ++it) {
            const int rr = it * 16 + rr0;
            const bf16x8 v = *(const bf16x8*)(lds + rr * 520 + cc * 2);
            *(bf16x8*)(Call + (row0 + rr) * (size_t)Ntot + col0 + cc) = v;
        }
    }
}

// ---------------------------------------------------------------------------
// Combine: y[n][c] = sum_k gate * (out[slot][c] + b2[e][c]); writes all of y.
// ---------------------------------------------------------------------------
__global__ __launch_bounds__(256) void k_combine(
    const __bf16* __restrict__ outb, const int* __restrict__ slot,
    const float* __restrict__ gates, const int* __restrict__ tidx,
    const float* __restrict__ b2, float* __restrict__ y)
{
    const int n = blockIdx.x;
    const int t = threadIdx.x;
    const int c = t * 4;
    float r0 = 0.f, r1 = 0.f, r2 = 0.f, r3 = 0.f;
#pragma unroll
    for (int k = 0; k < KTOP; ++k) {
        const int s = slot[n * 2 + k];
        if (s < 0) continue;
        const float g = gates[n * 2 + k];
        const int   e = tidx[n * 2 + k];
        const bf16x4 v = *(const bf16x4*)(outb + (size_t)s * CDIM + c);
        const float4 bb = *(const float4*)(b2 + (size_t)e * CDIM + c);
        r0 += g * ((float)v[0] + bb.x);
        r1 += g * ((float)v[1] + bb.y);
        r2 += g * ((float)v[2] + bb.z);
        r3 += g * ((float)v[3] + bb.w);
    }
    float4 o = make_float4(r0, r1, r2, r3);
    *(float4*)(y + (size_t)n * CDIM + c) = o;
}

// ---------------------------------------------------------------------------
extern "C" void kernel_launch(void* const* d_in, const int* in_sizes, int n_in,
                              void* d_out, int out_size, void* d_ws, size_t ws_size,
                              hipStream_t stream)
{
    const float* x  = (const float*)d_in[0];
    const float* rw = (const float*)d_in[1];
    const float* rb = (const float*)d_in[2];
    const float* w1 = (const float*)d_in[3];
    const float* b1 = (const float*)d_in[4];
    const float* w2 = (const float*)d_in[5];
    const float* b2 = (const float*)d_in[6];
    float* y = (float*)d_out;

    char* ws = (char*)d_ws;
    size_t off = 0;
    auto alloc = [&](size_t bytes) -> void* {
        void* p = ws + off;
        off = (off + bytes + 255) & ~(size_t)255;
        return p;
    };
    __bf16* w1t  = (__bf16*)alloc((size_t)NE * CDIM * HDIM * 2);   // [E][H][C]
    __bf16* w2t  = (__bf16*)alloc((size_t)NE * CDIM * HDIM * 2);   // [E][C][H]
    __bf16* inp  = (__bf16*)alloc((size_t)NE * CAPE * CDIM * 2);   // [E*cap][C]
    __bf16* hbuf = (__bf16*)alloc((size_t)NE * CAPE * HDIM * 2);   // [E*cap][H]
    __bf16* outb = (__bf16*)alloc((size_t)NE * CAPE * CDIM * 2);   // [E*cap][C]
    float*  probs = (float*)alloc((size_t)NTOK * NE * 4);
    float*  gates = (float*)alloc((size_t)NTOK * 2 * 4);
    int*    tidx  = (int*)alloc((size_t)NTOK * 2 * 4);
    int*    slot  = (int*)alloc((size_t)NTOK * 2 * 4);
    int*    tok   = (int*)alloc((size_t)NE * CAPE * 4);

    // 1. weight conversion (transposed to B^T layout, bf16) — 64x64 tiles
    k_transpose_bf16<<<dim3(HDIM / 64, CDIM / 64, NE), 256, 0, stream>>>(
        w1, w1t, CDIM, HDIM);
    k_transpose_bf16<<<dim3(CDIM / 64, HDIM / 64, NE), 256, 0, stream>>>(
        w2, w2t, HDIM, CDIM);

    // 2. router
    k_router<<<NTOK / 4, 256, 0, stream>>>(x, rw, rb, probs, gates, tidx);

    // 3. dispatch scan + aux loss (single block, log-scan)
    k_scan<<<1, 256, 0, stream>>>(tidx, probs, slot, tok, y + (size_t)NTOK * CDIM);

    // 4. gather expert inputs (bf16)
    k_gather<<<NE * CAPE, 256, 0, stream>>>(x, tok, inp);

    // 5. expert FFN — 256^2 8-wave 8-phase MFMA GEMMs + coalesced epilogue
    k_gemm8<true><<<dim3((NE * CAPE / 256) * (HDIM / 256)), 512, 0, stream>>>(
        inp, w1t, b1, hbuf, CDIM, HDIM, HDIM / 256, CAPE / 256);
    k_gemm8<false><<<dim3((NE * CAPE / 256) * (CDIM / 256)), 512, 0, stream>>>(
        hbuf, w2t, nullptr, outb, HDIM, CDIM, CDIM / 256, CAPE / 256);

    // 6. combine back to tokens (+aux already written by scan)
    k_combine<<<NTOK, 256, 0, stream>>>(outb, slot, gates, tidx, b2, y);
}